// Round 2
// baseline (2612.438 us; speedup 1.0000x reference)
//
#include <hip/hip_runtime.h>
#include <math.h>

#define BATCH   8
#define SEQ     512
#define IN_DIM  32
#define D_MODEL 512
#define N_LAYERS 4
#define D_INNER 1024
#define D_STATE 16
#define D_CONV  4
#define DT_RANK 32
#define NTOK    (BATCH * SEQ)   // 4096

__device__ __forceinline__ float sigmoidf_(float x) { return 1.f / (1.f + __expf(-x)); }

// sum x across each 16-lane row group via DPP (VALU pipe, no LDS traffic)
__device__ __forceinline__ float rowsum16(float x) {
    int t;
    t = __builtin_amdgcn_update_dpp(0, __float_as_int(x), 0xB1, 0xF, 0xF, true);  // quad_perm [1,0,3,2]
    x += __int_as_float(t);
    t = __builtin_amdgcn_update_dpp(0, __float_as_int(x), 0x4E, 0xF, 0xF, true);  // quad_perm [2,3,0,1]
    x += __int_as_float(t);
    t = __builtin_amdgcn_update_dpp(0, __float_as_int(x), 0x124, 0xF, 0xF, true); // row_ror:4
    x += __int_as_float(t);
    t = __builtin_amdgcn_update_dpp(0, __float_as_int(x), 0x128, 0xF, 0xF, true); // row_ror:8
    x += __int_as_float(t);
    return x;
}

// C[m,n] = act( dot(A[m,0:K], W[n,0:K]) + bias[n] ) + R[m,n]
// A: (M,lda) row-major (uses first K cols), W: (N,K) row-major, C/R: (M,N) stride ldc.
// act: 0 = none, 1 = softplus. 64x64 tile, 256 threads, 4x4 microtile, TK=16.
__global__ __launch_bounds__(256) void gemm_bt64(
    const float* __restrict__ A, int lda,
    const float* __restrict__ W,
    const float* __restrict__ bias,
    const float* __restrict__ R,
    float* __restrict__ C,
    int N, int K, int act, int ldc)
{
    __shared__ __align__(16) float As[16][64];
    __shared__ __align__(16) float Ws[16][64];
    const int tid = threadIdx.x;
    const int tx = tid & 15, ty = tid >> 4;
    const int m0 = blockIdx.y * 64, n0 = blockIdx.x * 64;
    const int lm = tid >> 2;            // 0..63: tile row loaded by this thread
    const int lk = (tid & 3) * 4;       // 0,4,8,12: k quad

    float acc[4][4] = {};
    for (int k0 = 0; k0 < K; k0 += 16) {
        float4 av = *(const float4*)&A[(size_t)(m0 + lm) * lda + k0 + lk];
        float4 wv = *(const float4*)&W[(size_t)(n0 + lm) * K   + k0 + lk];
        As[lk + 0][lm] = av.x; As[lk + 1][lm] = av.y; As[lk + 2][lm] = av.z; As[lk + 3][lm] = av.w;
        Ws[lk + 0][lm] = wv.x; Ws[lk + 1][lm] = wv.y; Ws[lk + 2][lm] = wv.z; Ws[lk + 3][lm] = wv.w;
        __syncthreads();
        #pragma unroll
        for (int k = 0; k < 16; ++k) {
            float4 a4 = *(const float4*)&As[k][ty * 4];
            float4 b4 = *(const float4*)&Ws[k][tx * 4];
            float a[4] = {a4.x, a4.y, a4.z, a4.w};
            float b[4] = {b4.x, b4.y, b4.z, b4.w};
            #pragma unroll
            for (int i = 0; i < 4; ++i)
                #pragma unroll
                for (int j = 0; j < 4; ++j)
                    acc[i][j] = fmaf(a[i], b[j], acc[i][j]);
        }
        __syncthreads();
    }
    #pragma unroll
    for (int i = 0; i < 4; ++i) {
        const int m = m0 + ty * 4 + i;
        #pragma unroll
        for (int j = 0; j < 4; ++j) {
            const int n = n0 + tx * 4 + j;
            float v = acc[i][j];
            if (bias) v += bias[n];
            if (act == 1) v = (v > 20.f) ? v : log1pf(__expf(v));   // softplus
            if (R) v += R[(size_t)m * ldc + n];
            C[(size_t)m * ldc + n] = v;
        }
    }
}

// xn[tok,:] = h[tok,:] * rsqrt(mean(h^2)+1e-5) * w
__global__ __launch_bounds__(256) void rmsnorm_kernel(
    const float* __restrict__ h, const float* __restrict__ w, float* __restrict__ xn)
{
    const int tok = blockIdx.x, tid = threadIdx.x;
    const float* row = h + (size_t)tok * D_MODEL;
    float v0 = row[tid], v1 = row[tid + 256];
    float s = v0 * v0 + v1 * v1;
    #pragma unroll
    for (int off = 32; off > 0; off >>= 1) s += __shfl_down(s, off, 64);
    __shared__ float ss[4];
    if ((tid & 63) == 0) ss[tid >> 6] = s;
    __syncthreads();
    const float total = ss[0] + ss[1] + ss[2] + ss[3];
    const float scale = rsqrtf(total * (1.f / (float)D_MODEL) + 1e-5f);
    float* orow = xn + (size_t)tok * D_MODEL;
    orow[tid]       = v0 * scale * w[tid];
    orow[tid + 256] = v1 * scale * w[tid + 256];
}

// c < D_INNER:  xr[tok,c] = silu(causal_dwconv(xz[:, c]) + cb[c])
// c >= D_INNER: xz[tok,c] = silu(xz[tok,c])   (gate precompute, in-place on z-half)
__global__ __launch_bounds__(256) void conv_silu_kernel(
    float* __restrict__ xz, const float* __restrict__ cw,
    const float* __restrict__ cb, float* __restrict__ xr)
{
    const int idx = blockIdx.x * 256 + threadIdx.x;   // over NTOK*2*D_INNER
    const int c   = idx & (2 * D_INNER - 1);
    const int tok = idx >> 11;
    if (c < D_INNER) {
        const int l = tok & (SEQ - 1);
        float acc = cb[c];
        #pragma unroll
        for (int k = 0; k < D_CONV; ++k) {
            const int t = l - (D_CONV - 1) + k;
            if (t >= 0)
                acc = fmaf(xz[(size_t)(tok + t - l) * (2 * D_INNER) + c], cw[c * D_CONV + k], acc);
        }
        xr[(size_t)tok * D_INNER + c] = acc * sigmoidf_(acc);
    } else {
        const float v = xz[idx];
        xz[idx] = v * sigmoidf_(v);
    }
}

// selective scan: one thread per (d, n) state-channel; 16 lanes per d-channel.
// block = 256 threads = 16 channels of one batch; grid = (D_INNER/16, BATCH) = 512 blocks.
// B/C staged interleaved in LDS (one ds_read_b64 per step); sum over n via DPP rowsum16.
// gate = xz z-half (pre-silu'd); y written into xz x-half (disjoint columns).
__global__ __launch_bounds__(256) void scan_kernel(
    const float* __restrict__ delta, const float* __restrict__ xrp,
    const float* __restrict__ dbc,   const float* __restrict__ gate,
    const float* __restrict__ A_log, const float* __restrict__ Dp,
    float* __restrict__ y)
{
    __shared__ __align__(16) float2 sBC[SEQ * 16];   // 64 KB
    const int b   = blockIdx.y;
    const int tid = threadIdx.x;
    const int n   = tid & 15;
    const int d   = blockIdx.x * 16 + (tid >> 4);

    for (int idx = tid; idx < SEQ * 16; idx += 256) {
        const float* row = dbc + ((size_t)(b * SEQ) + (idx >> 4)) * 64;
        float2 p;
        p.x = row[32 + (idx & 15)];   // B_n
        p.y = row[48 + (idx & 15)];   // C_n
        sBC[idx] = p;
    }
    __syncthreads();

    const float An = -__expf(A_log[(size_t)d * D_STATE + n]);
    const float Dd = Dp[d];
    const float* dp = delta + (size_t)b * SEQ * D_INNER + d;
    const float* xp = xrp   + (size_t)b * SEQ * D_INNER + d;
    const float* gp = gate  + (size_t)b * SEQ * 2 * D_INNER + d;
    float*       yp = y     + (size_t)b * SEQ * 2 * D_INNER + d;

    float h = 0.f;
    #pragma unroll 4
    for (int l = 0; l < SEQ; ++l) {
        const float dv = dp[(size_t)l * D_INNER];
        const float xv = xp[(size_t)l * D_INNER];
        const float2 bc = sBC[l * 16 + n];
        const float e = __expf(dv * An);
        h = fmaf(e, h, dv * xv * bc.x);
        float p = h * bc.y;
        p = rowsum16(p);
        if (n == 0) {
            const float g = gp[(size_t)l * 2 * D_INNER];
            yp[(size_t)l * 2 * D_INNER] = fmaf(Dd, xv, p) * g;
        }
    }
}

// d1[b,j] = relu(h[b,last,:] @ w1[j,:] + b1[j]); block per b, thread per j (256)
__global__ __launch_bounds__(256) void dec1_kernel(
    const float* __restrict__ h, const float* __restrict__ w1,
    const float* __restrict__ b1, float* __restrict__ d1)
{
    __shared__ __align__(16) float hr[D_MODEL];
    const int b = blockIdx.x, j = threadIdx.x;
    const float* row = h + ((size_t)(b * SEQ + SEQ - 1)) * D_MODEL;
    hr[j] = row[j];
    hr[j + 256] = row[j + 256];
    __syncthreads();
    float acc = b1[j];
    const float* wr = w1 + (size_t)j * D_MODEL;
    for (int k = 0; k < D_MODEL; k += 4) {
        const float4 wv = *(const float4*)&wr[k];
        const float4 hv = *(const float4*)&hr[k];
        acc = fmaf(wv.x, hv.x, acc); acc = fmaf(wv.y, hv.y, acc);
        acc = fmaf(wv.z, hv.z, acc); acc = fmaf(wv.w, hv.w, acc);
    }
    d1[b * 256 + j] = fmaxf(acc, 0.f);
}

// out[b] = d1[b,:] @ w2 + b2; block per b, 64 threads (1 wave)
__global__ void dec2_kernel(const float* __restrict__ d1, const float* __restrict__ w2,
                            const float* __restrict__ b2, float* __restrict__ out)
{
    const int b = blockIdx.x, t = threadIdx.x;
    float acc = 0.f;
    for (int k = t; k < 256; k += 64) acc = fmaf(d1[b * 256 + k], w2[k], acc);
    #pragma unroll
    for (int off = 32; off > 0; off >>= 1) acc += __shfl_down(acc, off, 64);
    if (t == 0) out[b] = acc + b2[0];
}

extern "C" void kernel_launch(void* const* d_in, const int* in_sizes, int n_in,
                              void* d_out, int out_size, void* d_ws, size_t ws_size,
                              hipStream_t stream)
{
    const float* x      = (const float*)d_in[0];
    const float* enc_w  = (const float*)d_in[1];
    const float* enc_b  = (const float*)d_in[2];
    const float* in_w   = (const float*)d_in[3];
    const float* conv_w = (const float*)d_in[4];
    const float* conv_b = (const float*)d_in[5];
    const float* xp_w   = (const float*)d_in[6];
    const float* dtp_w  = (const float*)d_in[7];
    const float* dtp_b  = (const float*)d_in[8];
    const float* A_log  = (const float*)d_in[9];
    const float* Dp     = (const float*)d_in[10];
    const float* out_w  = (const float*)d_in[11];
    const float* norm_w = (const float*)d_in[12];
    const float* dec_w1 = (const float*)d_in[13];
    const float* dec_b1 = (const float*)d_in[14];
    const float* dec_w2 = (const float*)d_in[15];
    const float* dec_b2 = (const float*)d_in[16];
    float* out = (float*)d_out;

    // workspace layout (floats)
    float* ws    = (float*)d_ws;
    float* h     = ws;                                   // NTOK*512
    float* xn    = h     + (size_t)NTOK * D_MODEL;       // NTOK*512
    float* xz    = xn    + (size_t)NTOK * D_MODEL;       // NTOK*2048
    float* xr    = xz    + (size_t)NTOK * 2 * D_INNER;   // NTOK*1024
    float* delta = xr    + (size_t)NTOK * D_INNER;       // NTOK*1024
    float* dbc   = delta + (size_t)NTOK * D_INNER;       // NTOK*64
    float* d1    = dbc   + (size_t)NTOK * 64;            // 2048

    // encoder: h = x @ enc_w.T + enc_b
    gemm_bt64<<<dim3(D_MODEL / 64, NTOK / 64), 256, 0, stream>>>(
        x, IN_DIM, enc_w, enc_b, nullptr, h, D_MODEL, IN_DIM, 0, D_MODEL);

    for (int i = 0; i < N_LAYERS; ++i) {
        rmsnorm_kernel<<<NTOK, 256, 0, stream>>>(h, norm_w + (size_t)i * D_MODEL, xn);

        // xz = xn @ in_proj_w[i].T   (4096 x 2048, K=512)
        gemm_bt64<<<dim3(2 * D_INNER / 64, NTOK / 64), 256, 0, stream>>>(
            xn, D_MODEL, in_w + (size_t)i * 2 * D_INNER * D_MODEL,
            nullptr, nullptr, xz, 2 * D_INNER, D_MODEL, 0, 2 * D_INNER);

        // xr = silu(causal_dwconv(xz[:, :D_INNER]) + cb); xz z-half -> silu in place
        conv_silu_kernel<<<NTOK * 2 * D_INNER / 256, 256, 0, stream>>>(
            xz, conv_w + (size_t)i * D_INNER * D_CONV, conv_b + (size_t)i * D_INNER, xr);

        // dbc = xr @ x_proj_w[i].T   (4096 x 64, K=1024)
        gemm_bt64<<<dim3(1, NTOK / 64), 256, 0, stream>>>(
            xr, D_INNER, xp_w + (size_t)i * 64 * D_INNER,
            nullptr, nullptr, dbc, 64, D_INNER, 0, 64);

        // delta = softplus(dbc[:, :32] @ dt_proj_w[i].T + dt_proj_b[i])  (4096 x 1024, K=32)
        gemm_bt64<<<dim3(D_INNER / 64, NTOK / 64), 256, 0, stream>>>(
            dbc, 64, dtp_w + (size_t)i * D_INNER * DT_RANK,
            dtp_b + (size_t)i * D_INNER, nullptr, delta, D_INNER, DT_RANK, 1, D_INNER);

        // selective scan + D skip + gate; y -> xz x-half (stride 2048)
        scan_kernel<<<dim3(D_INNER / 16, BATCH), 256, 0, stream>>>(
            delta, xr, dbc, xz + D_INNER,
            A_log + (size_t)i * D_INNER * D_STATE, Dp + (size_t)i * D_INNER, xz);

        // h = h + y @ out_proj_w[i].T   (4096 x 512, K=1024, A stride 2048)
        gemm_bt64<<<dim3(D_MODEL / 64, NTOK / 64), 256, 0, stream>>>(
            xz, 2 * D_INNER, out_w + (size_t)i * D_MODEL * D_INNER,
            nullptr, h, h, D_MODEL, D_INNER, 0, D_MODEL);
    }

    dec1_kernel<<<BATCH, 256, 0, stream>>>(h, dec_w1, dec_b1, d1);
    dec2_kernel<<<BATCH, 64, 0, stream>>>(d1, dec_w2, dec_b2, out);
}

// Round 3
// 1660.018 us; speedup vs baseline: 1.5737x; 1.5737x over previous
//
#include <hip/hip_runtime.h>
#include <math.h>

#define BATCH   8
#define SEQ     512
#define IN_DIM  32
#define D_MODEL 512
#define N_LAYERS 4
#define D_INNER 1024
#define D_STATE 16
#define D_CONV  4
#define DT_RANK 32
#define NTOK    (BATCH * SEQ)   // 4096
#define CHUNK   128             // scan L-chunk staged in LDS

__device__ __forceinline__ float sigmoidf_(float x) { return 1.f / (1.f + __expf(-x)); }

// sum x across each 16-lane row group via DPP (VALU pipe, no LDS traffic)
__device__ __forceinline__ float rowsum16(float x) {
    int t;
    t = __builtin_amdgcn_update_dpp(0, __float_as_int(x), 0xB1, 0xF, 0xF, true);  // quad_perm [1,0,3,2]
    x += __int_as_float(t);
    t = __builtin_amdgcn_update_dpp(0, __float_as_int(x), 0x4E, 0xF, 0xF, true);  // quad_perm [2,3,0,1]
    x += __int_as_float(t);
    t = __builtin_amdgcn_update_dpp(0, __float_as_int(x), 0x124, 0xF, 0xF, true); // row_ror:4
    x += __int_as_float(t);
    t = __builtin_amdgcn_update_dpp(0, __float_as_int(x), 0x128, 0xF, 0xF, true); // row_ror:8
    x += __int_as_float(t);
    return x;
}

// C[m,n] = act( dot(A[m,0:K], W[n,0:K]) + bias[n] ) + R[m,n]
// A: (M,lda) row-major (uses first K cols), W: (N,K) row-major, C/R: (M,N) stride ldc.
// act: 0 = none, 1 = softplus. 64x64 tile, 256 threads, 4x4 microtile, TK=16.
__global__ __launch_bounds__(256) void gemm_bt64(
    const float* __restrict__ A, int lda,
    const float* __restrict__ W,
    const float* __restrict__ bias,
    const float* __restrict__ R,
    float* __restrict__ C,
    int N, int K, int act, int ldc)
{
    __shared__ __align__(16) float As[16][64];
    __shared__ __align__(16) float Ws[16][64];
    const int tid = threadIdx.x;
    const int tx = tid & 15, ty = tid >> 4;
    const int m0 = blockIdx.y * 64, n0 = blockIdx.x * 64;
    const int lm = tid >> 2;            // 0..63: tile row loaded by this thread
    const int lk = (tid & 3) * 4;       // 0,4,8,12: k quad

    float acc[4][4] = {};
    for (int k0 = 0; k0 < K; k0 += 16) {
        float4 av = *(const float4*)&A[(size_t)(m0 + lm) * lda + k0 + lk];
        float4 wv = *(const float4*)&W[(size_t)(n0 + lm) * K   + k0 + lk];
        As[lk + 0][lm] = av.x; As[lk + 1][lm] = av.y; As[lk + 2][lm] = av.z; As[lk + 3][lm] = av.w;
        Ws[lk + 0][lm] = wv.x; Ws[lk + 1][lm] = wv.y; Ws[lk + 2][lm] = wv.z; Ws[lk + 3][lm] = wv.w;
        __syncthreads();
        #pragma unroll
        for (int k = 0; k < 16; ++k) {
            float4 a4 = *(const float4*)&As[k][ty * 4];
            float4 b4 = *(const float4*)&Ws[k][tx * 4];
            float a[4] = {a4.x, a4.y, a4.z, a4.w};
            float b[4] = {b4.x, b4.y, b4.z, b4.w};
            #pragma unroll
            for (int i = 0; i < 4; ++i)
                #pragma unroll
                for (int j = 0; j < 4; ++j)
                    acc[i][j] = fmaf(a[i], b[j], acc[i][j]);
        }
        __syncthreads();
    }
    #pragma unroll
    for (int i = 0; i < 4; ++i) {
        const int m = m0 + ty * 4 + i;
        #pragma unroll
        for (int j = 0; j < 4; ++j) {
            const int n = n0 + tx * 4 + j;
            float v = acc[i][j];
            if (bias) v += bias[n];
            if (act == 1) v = (v > 20.f) ? v : log1pf(__expf(v));   // softplus
            if (R) v += R[(size_t)m * ldc + n];
            C[(size_t)m * ldc + n] = v;
        }
    }
}

// xn[tok,:] = h[tok,:] * rsqrt(mean(h^2)+1e-5) * w
__global__ __launch_bounds__(256) void rmsnorm_kernel(
    const float* __restrict__ h, const float* __restrict__ w, float* __restrict__ xn)
{
    const int tok = blockIdx.x, tid = threadIdx.x;
    const float* row = h + (size_t)tok * D_MODEL;
    float v0 = row[tid], v1 = row[tid + 256];
    float s = v0 * v0 + v1 * v1;
    #pragma unroll
    for (int off = 32; off > 0; off >>= 1) s += __shfl_down(s, off, 64);
    __shared__ float ss[4];
    if ((tid & 63) == 0) ss[tid >> 6] = s;
    __syncthreads();
    const float total = ss[0] + ss[1] + ss[2] + ss[3];
    const float scale = rsqrtf(total * (1.f / (float)D_MODEL) + 1e-5f);
    float* orow = xn + (size_t)tok * D_MODEL;
    orow[tid]       = v0 * scale * w[tid];
    orow[tid + 256] = v1 * scale * w[tid + 256];
}

// c < D_INNER:  xr[tok,c] = silu(causal_dwconv(xz[:, c]) + cb[c])
// c >= D_INNER: xz[tok,c] = silu(xz[tok,c])   (gate precompute, in-place on z-half)
__global__ __launch_bounds__(256) void conv_silu_kernel(
    float* __restrict__ xz, const float* __restrict__ cw,
    const float* __restrict__ cb, float* __restrict__ xr)
{
    const int idx = blockIdx.x * 256 + threadIdx.x;   // over NTOK*2*D_INNER
    const int c   = idx & (2 * D_INNER - 1);
    const int tok = idx >> 11;
    if (c < D_INNER) {
        const int l = tok & (SEQ - 1);
        float acc = cb[c];
        #pragma unroll
        for (int k = 0; k < D_CONV; ++k) {
            const int t = l - (D_CONV - 1) + k;
            if (t >= 0)
                acc = fmaf(xz[(size_t)(tok + t - l) * (2 * D_INNER) + c], cw[c * D_CONV + k], acc);
        }
        xr[(size_t)tok * D_INNER + c] = acc * sigmoidf_(acc);
    } else {
        const float v = xz[idx];
        xz[idx] = v * sigmoidf_(v);
    }
}

// selective scan, LDS-chunked. Thread = (d, n); 16 lanes per d-channel.
// Block = 256 threads = 16 channels of one batch; grid = (64, 8) = 512 blocks.
// Per chunk of 128 steps: bulk-stage (delta,x) and (B,C) into LDS coalesced,
// run recurrence from LDS, accumulate y in LDS, bulk-store y*gate over xr (in place).
__global__ __launch_bounds__(256) void scan_kernel(
    const float* __restrict__ delta, const float* __restrict__ xrp,
    const float* __restrict__ dbc,   const float* __restrict__ xz,
    const float* __restrict__ A_log, const float* __restrict__ Dp,
    float* __restrict__ y)   // y == xr (in-place, chunk-disjoint)
{
    __shared__ __align__(16) float2 sDX[CHUNK * 16];  // (delta, x)   16 KB
    __shared__ __align__(16) float2 sBC[CHUNK * 16];  // (B_n, C_n)   16 KB
    __shared__ __align__(16) float  sY [CHUNK * 16];  //               8 KB
    const int b   = blockIdx.y;
    const int tid = threadIdx.x;
    const int n   = tid & 15;
    const int dl  = tid >> 4;              // 0..15 local channel
    const int d0  = blockIdx.x * 16;
    const int d   = d0 + dl;

    const float An = -__expf(A_log[(size_t)d * D_STATE + n]);
    const float Dd = Dp[d];

    float h = 0.f;
    for (int l0 = 0; l0 < SEQ; l0 += CHUNK) {
        // ---- stage (delta, x) interleaved: rows of 16 floats as 4 float4s ----
        #pragma unroll
        for (int it = 0; it < CHUNK * 4 / 256; ++it) {
            const int idx = it * 256 + tid;
            const int l = idx >> 2, q = idx & 3;
            const size_t row = (size_t)(b * SEQ + l0 + l);
            const float4 dv = *(const float4*)&delta[row * D_INNER + d0 + q * 4];
            const float4 xv = *(const float4*)&xrp  [row * D_INNER + d0 + q * 4];
            float2* o = &sDX[l * 16 + q * 4];
            o[0] = make_float2(dv.x, xv.x);
            o[1] = make_float2(dv.y, xv.y);
            o[2] = make_float2(dv.z, xv.z);
            o[3] = make_float2(dv.w, xv.w);
        }
        // ---- stage (B, C) interleaved from dbc[:, 32:64] ----
        #pragma unroll
        for (int it = 0; it < CHUNK * 8 / 256; ++it) {
            const int idx = it * 256 + tid;
            const int l = idx >> 3, q = idx & 7;
            const size_t row = (size_t)(b * SEQ + l0 + l);
            const float4 v = *(const float4*)&dbc[row * 64 + 32 + q * 4];
            float* base = (float*)&sBC[l * 16];
            if (q < 4) {         // B components -> .x
                const int c = q * 4;
                base[2*(c+0)] = v.x; base[2*(c+1)] = v.y; base[2*(c+2)] = v.z; base[2*(c+3)] = v.w;
            } else {             // C components -> .y
                const int c = (q - 4) * 4;
                base[2*(c+0)+1] = v.x; base[2*(c+1)+1] = v.y; base[2*(c+2)+1] = v.z; base[2*(c+3)+1] = v.w;
            }
        }
        __syncthreads();

        // ---- recurrence from LDS ----
        #pragma unroll 4
        for (int l = 0; l < CHUNK; ++l) {
            const float2 dx = sDX[l * 16 + dl];   // broadcast across 16 lanes
            const float2 bc = sBC[l * 16 + n];    // conflict-free, 4-way broadcast
            const float e = __expf(dx.x * An);
            h = fmaf(e, h, dx.x * dx.y * bc.x);
            const float p = rowsum16(h * bc.y);
            if (n == 0) sY[l * 16 + dl] = fmaf(Dd, dx.y, p);
        }
        __syncthreads();

        // ---- bulk store: y = sY * gate (gate = pre-silu'd z-half of xz) ----
        #pragma unroll
        for (int it = 0; it < CHUNK * 4 / 256; ++it) {
            const int idx = it * 256 + tid;
            const int l = idx >> 2, q = idx & 3;
            const size_t row = (size_t)(b * SEQ + l0 + l);
            const float4 g4 = *(const float4*)&xz[row * 2 * D_INNER + D_INNER + d0 + q * 4];
            const float4 yv = *(const float4*)&sY[l * 16 + q * 4];
            float4 o;
            o.x = yv.x * g4.x; o.y = yv.y * g4.y; o.z = yv.z * g4.z; o.w = yv.w * g4.w;
            *(float4*)&y[row * D_INNER + d0 + q * 4] = o;
        }
        // next stage's __syncthreads() orders this store-phase before sY reuse
    }
}

// d1[b,j] = relu(h[b,last,:] @ w1[j,:] + b1[j]); block per b, thread per j (256)
__global__ __launch_bounds__(256) void dec1_kernel(
    const float* __restrict__ h, const float* __restrict__ w1,
    const float* __restrict__ b1, float* __restrict__ d1)
{
    __shared__ __align__(16) float hr[D_MODEL];
    const int b = blockIdx.x, j = threadIdx.x;
    const float* row = h + ((size_t)(b * SEQ + SEQ - 1)) * D_MODEL;
    hr[j] = row[j];
    hr[j + 256] = row[j + 256];
    __syncthreads();
    float acc = b1[j];
    const float* wr = w1 + (size_t)j * D_MODEL;
    for (int k = 0; k < D_MODEL; k += 4) {
        const float4 wv = *(const float4*)&wr[k];
        const float4 hv = *(const float4*)&hr[k];
        acc = fmaf(wv.x, hv.x, acc); acc = fmaf(wv.y, hv.y, acc);
        acc = fmaf(wv.z, hv.z, acc); acc = fmaf(wv.w, hv.w, acc);
    }
    d1[b * 256 + j] = fmaxf(acc, 0.f);
}

// out[b] = d1[b,:] @ w2 + b2; block per b, 64 threads (1 wave)
__global__ void dec2_kernel(const float* __restrict__ d1, const float* __restrict__ w2,
                            const float* __restrict__ b2, float* __restrict__ out)
{
    const int b = blockIdx.x, t = threadIdx.x;
    float acc = 0.f;
    for (int k = t; k < 256; k += 64) acc = fmaf(d1[b * 256 + k], w2[k], acc);
    #pragma unroll
    for (int off = 32; off > 0; off >>= 1) acc += __shfl_down(acc, off, 64);
    if (t == 0) out[b] = acc + b2[0];
}

extern "C" void kernel_launch(void* const* d_in, const int* in_sizes, int n_in,
                              void* d_out, int out_size, void* d_ws, size_t ws_size,
                              hipStream_t stream)
{
    const float* x      = (const float*)d_in[0];
    const float* enc_w  = (const float*)d_in[1];
    const float* enc_b  = (const float*)d_in[2];
    const float* in_w   = (const float*)d_in[3];
    const float* conv_w = (const float*)d_in[4];
    const float* conv_b = (const float*)d_in[5];
    const float* xp_w   = (const float*)d_in[6];
    const float* dtp_w  = (const float*)d_in[7];
    const float* dtp_b  = (const float*)d_in[8];
    const float* A_log  = (const float*)d_in[9];
    const float* Dp     = (const float*)d_in[10];
    const float* out_w  = (const float*)d_in[11];
    const float* norm_w = (const float*)d_in[12];
    const float* dec_w1 = (const float*)d_in[13];
    const float* dec_b1 = (const float*)d_in[14];
    const float* dec_w2 = (const float*)d_in[15];
    const float* dec_b2 = (const float*)d_in[16];
    float* out = (float*)d_out;

    // workspace layout (floats)
    float* ws    = (float*)d_ws;
    float* h     = ws;                                   // NTOK*512
    float* xn    = h     + (size_t)NTOK * D_MODEL;       // NTOK*512
    float* xz    = xn    + (size_t)NTOK * D_MODEL;       // NTOK*2048
    float* xr    = xz    + (size_t)NTOK * 2 * D_INNER;   // NTOK*1024
    float* delta = xr    + (size_t)NTOK * D_INNER;       // NTOK*1024
    float* dbc   = delta + (size_t)NTOK * D_INNER;       // NTOK*64
    float* d1    = dbc   + (size_t)NTOK * 64;            // 2048

    // encoder: h = x @ enc_w.T + enc_b
    gemm_bt64<<<dim3(D_MODEL / 64, NTOK / 64), 256, 0, stream>>>(
        x, IN_DIM, enc_w, enc_b, nullptr, h, D_MODEL, IN_DIM, 0, D_MODEL);

    for (int i = 0; i < N_LAYERS; ++i) {
        rmsnorm_kernel<<<NTOK, 256, 0, stream>>>(h, norm_w + (size_t)i * D_MODEL, xn);

        // xz = xn @ in_proj_w[i].T   (4096 x 2048, K=512)
        gemm_bt64<<<dim3(2 * D_INNER / 64, NTOK / 64), 256, 0, stream>>>(
            xn, D_MODEL, in_w + (size_t)i * 2 * D_INNER * D_MODEL,
            nullptr, nullptr, xz, 2 * D_INNER, D_MODEL, 0, 2 * D_INNER);

        // xr = silu(causal_dwconv(xz[:, :D_INNER]) + cb); xz z-half -> silu in place
        conv_silu_kernel<<<NTOK * 2 * D_INNER / 256, 256, 0, stream>>>(
            xz, conv_w + (size_t)i * D_INNER * D_CONV, conv_b + (size_t)i * D_INNER, xr);

        // dbc = xr @ x_proj_w[i].T   (4096 x 64, K=1024)
        gemm_bt64<<<dim3(1, NTOK / 64), 256, 0, stream>>>(
            xr, D_INNER, xp_w + (size_t)i * 64 * D_INNER,
            nullptr, nullptr, dbc, 64, D_INNER, 0, 64);

        // delta = softplus(dbc[:, :32] @ dt_proj_w[i].T + dt_proj_b[i])  (4096 x 1024, K=32)
        gemm_bt64<<<dim3(D_INNER / 64, NTOK / 64), 256, 0, stream>>>(
            dbc, 64, dtp_w + (size_t)i * D_INNER * DT_RANK,
            dtp_b + (size_t)i * D_INNER, nullptr, delta, D_INNER, DT_RANK, 1, D_INNER);

        // selective scan + D skip + gate; y written in-place over xr
        scan_kernel<<<dim3(D_INNER / 16, BATCH), 256, 0, stream>>>(
            delta, xr, dbc, xz,
            A_log + (size_t)i * D_INNER * D_STATE, Dp + (size_t)i * D_INNER, xr);

        // h = h + y @ out_proj_w[i].T   (4096 x 512, K=1024)
        gemm_bt64<<<dim3(D_MODEL / 64, NTOK / 64), 256, 0, stream>>>(
            xr, D_INNER, out_w + (size_t)i * D_MODEL * D_INNER,
            nullptr, h, h, D_MODEL, D_INNER, 0, D_MODEL);
    }

    dec1_kernel<<<BATCH, 256, 0, stream>>>(h, dec_w1, dec_b1, d1);
    dec2_kernel<<<BATCH, 64, 0, stream>>>(d1, dec_w2, dec_b2, out);
}

// Round 4
// 1075.415 us; speedup vs baseline: 2.4292x; 1.5436x over previous
//
#include <hip/hip_runtime.h>
#include <math.h>

#define BATCH   8
#define SEQ     512
#define IN_DIM  32
#define D_MODEL 512
#define N_LAYERS 4
#define D_INNER 1024
#define D_STATE 16
#define D_CONV  4
#define DT_RANK 32
#define NTOK    (BATCH * SEQ)   // 4096
#define CHUNK   128             // scan L-chunk staged in LDS

typedef __attribute__((ext_vector_type(8))) short short8_t;
typedef __attribute__((ext_vector_type(4))) float floatx4;

__device__ __forceinline__ float sigmoidf_(float x) { return 1.f / (1.f + __expf(-x)); }

// fp32 -> bf16 round-to-nearest-even (finite inputs)
__device__ __forceinline__ unsigned short f2bf(float f) {
    unsigned int u = __float_as_uint(f);
    return (unsigned short)((u + 0x7fffu + ((u >> 16) & 1u)) >> 16);
}

// sum x across each 16-lane row group via DPP (VALU pipe, no LDS traffic)
__device__ __forceinline__ float rowsum16(float x) {
    int t;
    t = __builtin_amdgcn_update_dpp(0, __float_as_int(x), 0xB1, 0xF, 0xF, true);  // quad_perm [1,0,3,2]
    x += __int_as_float(t);
    t = __builtin_amdgcn_update_dpp(0, __float_as_int(x), 0x4E, 0xF, 0xF, true);  // quad_perm [2,3,0,1]
    x += __int_as_float(t);
    t = __builtin_amdgcn_update_dpp(0, __float_as_int(x), 0x124, 0xF, 0xF, true); // row_ror:4
    x += __int_as_float(t);
    t = __builtin_amdgcn_update_dpp(0, __float_as_int(x), 0x128, 0xF, 0xF, true); // row_ror:8
    x += __int_as_float(t);
    return x;
}

// elementwise fp32 -> bf16 cast; n % 4 == 0
__global__ __launch_bounds__(256) void cast_bf16_kernel(
    const float* __restrict__ in, unsigned short* __restrict__ out, int n)
{
    const int i = (blockIdx.x * 256 + threadIdx.x) * 4;
    if (i >= n) return;
    const float4 v = *(const float4*)&in[i];
    ushort4 o;
    o.x = f2bf(v.x); o.y = f2bf(v.y); o.z = f2bf(v.z); o.w = f2bf(v.w);
    *(ushort4*)&out[i] = o;
}

// ---------------- bf16 MFMA GEMM ----------------
// C[m,n] = dot(A[m,0:K], W[n,0:K]) (+ R[m,n]); A,W bf16, C/R fp32.
// Block tile BM x BN, 4 waves in 2x2, wave tile (BM/2)x(BN/2) of 16x16 MFMAs, BK=32.
// LDS rows padded to 40 bf16 (20 banks) -> 2-way conflicts only (free).
template<int BM, int BN>
__global__ __launch_bounds__(256) void gemm_mfma(
    const unsigned short* __restrict__ A, int lda,
    const unsigned short* __restrict__ W,
    const float* __restrict__ R,
    float* __restrict__ C, int ldc, int K)
{
    constexpr int MT = BM / 32;       // 16-row tiles per wave (m)
    constexpr int NT = BN / 32;       // 16-col tiles per wave (n)
    constexpr int LDSP = 40;          // padded row stride (bf16 units)
    __shared__ __align__(16) unsigned short sA[BM * LDSP];
    __shared__ __align__(16) unsigned short sB[BN * LDSP];

    const int tid  = threadIdx.x;
    const int lane = tid & 63;
    const int wave = tid >> 6;
    const int wm0  = (wave >> 1) * (BM / 2);
    const int wn0  = (wave & 1) * (BN / 2);
    const int lrow = lane & 15;
    const int lko  = (lane >> 4) * 8;
    const int m0 = blockIdx.y * BM;
    const int n0 = blockIdx.x * BN;

    floatx4 acc[MT][NT];
    #pragma unroll
    for (int mt = 0; mt < MT; ++mt)
        #pragma unroll
        for (int nt = 0; nt < NT; ++nt)
            acc[mt][nt] = (floatx4){0.f, 0.f, 0.f, 0.f};

    for (int k0 = 0; k0 < K; k0 += 32) {
        #pragma unroll
        for (int it = 0; it < BM * 4 / 256; ++it) {
            const int idx = it * 256 + tid;
            const int r = idx >> 2, c = (idx & 3) * 8;
            *(short8_t*)&sA[r * LDSP + c] = *(const short8_t*)&A[(size_t)(m0 + r) * lda + k0 + c];
        }
        #pragma unroll
        for (int it = 0; it < BN * 4 / 256; ++it) {
            const int idx = it * 256 + tid;
            const int r = idx >> 2, c = (idx & 3) * 8;
            *(short8_t*)&sB[r * LDSP + c] = *(const short8_t*)&W[(size_t)(n0 + r) * K + k0 + c];
        }
        __syncthreads();
        short8_t af[MT], bfr[NT];
        #pragma unroll
        for (int mt = 0; mt < MT; ++mt)
            af[mt] = *(const short8_t*)&sA[(wm0 + mt * 16 + lrow) * LDSP + lko];
        #pragma unroll
        for (int nt = 0; nt < NT; ++nt)
            bfr[nt] = *(const short8_t*)&sB[(wn0 + nt * 16 + lrow) * LDSP + lko];
        #pragma unroll
        for (int mt = 0; mt < MT; ++mt)
            #pragma unroll
            for (int nt = 0; nt < NT; ++nt)
                acc[mt][nt] = __builtin_amdgcn_mfma_f32_16x16x32_bf16(af[mt], bfr[nt], acc[mt][nt], 0, 0, 0);
        __syncthreads();
    }

    #pragma unroll
    for (int mt = 0; mt < MT; ++mt) {
        const int mbase = m0 + wm0 + mt * 16 + (lane >> 4) * 4;
        #pragma unroll
        for (int nt = 0; nt < NT; ++nt) {
            const int n = n0 + wn0 + nt * 16 + (lane & 15);
            #pragma unroll
            for (int r = 0; r < 4; ++r) {
                float v = acc[mt][nt][r];
                if (R) v += R[(size_t)(mbase + r) * ldc + n];
                C[(size_t)(mbase + r) * ldc + n] = v;
            }
        }
    }
}

// ---------------- fp32 vector GEMM (small K paths) ----------------
__global__ __launch_bounds__(256) void gemm_bt64(
    const float* __restrict__ A, int lda,
    const float* __restrict__ W,
    const float* __restrict__ bias,
    const float* __restrict__ R,
    float* __restrict__ C,
    int N, int K, int act, int ldc)
{
    __shared__ __align__(16) float As[16][64];
    __shared__ __align__(16) float Ws[16][64];
    const int tid = threadIdx.x;
    const int tx = tid & 15, ty = tid >> 4;
    const int m0 = blockIdx.y * 64, n0 = blockIdx.x * 64;
    const int lm = tid >> 2;
    const int lk = (tid & 3) * 4;

    float acc[4][4] = {};
    for (int k0 = 0; k0 < K; k0 += 16) {
        float4 av = *(const float4*)&A[(size_t)(m0 + lm) * lda + k0 + lk];
        float4 wv = *(const float4*)&W[(size_t)(n0 + lm) * K   + k0 + lk];
        As[lk + 0][lm] = av.x; As[lk + 1][lm] = av.y; As[lk + 2][lm] = av.z; As[lk + 3][lm] = av.w;
        Ws[lk + 0][lm] = wv.x; Ws[lk + 1][lm] = wv.y; Ws[lk + 2][lm] = wv.z; Ws[lk + 3][lm] = wv.w;
        __syncthreads();
        #pragma unroll
        for (int k = 0; k < 16; ++k) {
            float4 a4 = *(const float4*)&As[k][ty * 4];
            float4 b4 = *(const float4*)&Ws[k][tx * 4];
            float a[4] = {a4.x, a4.y, a4.z, a4.w};
            float b[4] = {b4.x, b4.y, b4.z, b4.w};
            #pragma unroll
            for (int i = 0; i < 4; ++i)
                #pragma unroll
                for (int j = 0; j < 4; ++j)
                    acc[i][j] = fmaf(a[i], b[j], acc[i][j]);
        }
        __syncthreads();
    }
    #pragma unroll
    for (int i = 0; i < 4; ++i) {
        const int m = m0 + ty * 4 + i;
        #pragma unroll
        for (int j = 0; j < 4; ++j) {
            const int n = n0 + tx * 4 + j;
            float v = acc[i][j];
            if (bias) v += bias[n];
            if (act == 1) v = (v > 20.f) ? v : log1pf(__expf(v));   // softplus
            if (R) v += R[(size_t)m * ldc + n];
            C[(size_t)m * ldc + n] = v;
        }
    }
}

// xn_bf[tok,:] = bf16( h[tok,:] * rsqrt(mean(h^2)+1e-5) * w )
__global__ __launch_bounds__(256) void rmsnorm_kernel(
    const float* __restrict__ h, const float* __restrict__ w, unsigned short* __restrict__ xn)
{
    const int tok = blockIdx.x, tid = threadIdx.x;
    const float* row = h + (size_t)tok * D_MODEL;
    float v0 = row[tid], v1 = row[tid + 256];
    float s = v0 * v0 + v1 * v1;
    #pragma unroll
    for (int off = 32; off > 0; off >>= 1) s += __shfl_down(s, off, 64);
    __shared__ float ss[4];
    if ((tid & 63) == 0) ss[tid >> 6] = s;
    __syncthreads();
    const float total = ss[0] + ss[1] + ss[2] + ss[3];
    const float scale = rsqrtf(total * (1.f / (float)D_MODEL) + 1e-5f);
    unsigned short* orow = xn + (size_t)tok * D_MODEL;
    orow[tid]       = f2bf(v0 * scale * w[tid]);
    orow[tid + 256] = f2bf(v1 * scale * w[tid + 256]);
}

// c < D_INNER:  xr[tok,c] = silu(causal_dwconv(xz[:, c]) + cb[c])
// c >= D_INNER: xz[tok,c] = silu(xz[tok,c])   (gate precompute, in-place on z-half)
__global__ __launch_bounds__(256) void conv_silu_kernel(
    float* __restrict__ xz, const float* __restrict__ cw,
    const float* __restrict__ cb, float* __restrict__ xr)
{
    const int idx = blockIdx.x * 256 + threadIdx.x;   // over NTOK*2*D_INNER
    const int c   = idx & (2 * D_INNER - 1);
    const int tok = idx >> 11;
    if (c < D_INNER) {
        const int l = tok & (SEQ - 1);
        float acc = cb[c];
        #pragma unroll
        for (int k = 0; k < D_CONV; ++k) {
            const int t = l - (D_CONV - 1) + k;
            if (t >= 0)
                acc = fmaf(xz[(size_t)(tok + t - l) * (2 * D_INNER) + c], cw[c * D_CONV + k], acc);
        }
        xr[(size_t)tok * D_INNER + c] = acc * sigmoidf_(acc);
    } else {
        const float v = xz[idx];
        xz[idx] = v * sigmoidf_(v);
    }
}

// selective scan, LDS-chunked (see R3). Output y now bf16 (feeds MFMA out_proj).
__global__ __launch_bounds__(256) void scan_kernel(
    const float* __restrict__ delta, const float* __restrict__ xrp,
    const float* __restrict__ dbc,   const float* __restrict__ xz,
    const float* __restrict__ A_log, const float* __restrict__ Dp,
    unsigned short* __restrict__ y)
{
    __shared__ __align__(16) float2 sDX[CHUNK * 16];
    __shared__ __align__(16) float2 sBC[CHUNK * 16];
    __shared__ __align__(16) float  sY [CHUNK * 16];
    const int b   = blockIdx.y;
    const int tid = threadIdx.x;
    const int n   = tid & 15;
    const int dl  = tid >> 4;
    const int d0  = blockIdx.x * 16;
    const int d   = d0 + dl;

    const float An = -__expf(A_log[(size_t)d * D_STATE + n]);
    const float Dd = Dp[d];

    float h = 0.f;
    for (int l0 = 0; l0 < SEQ; l0 += CHUNK) {
        #pragma unroll
        for (int it = 0; it < CHUNK * 4 / 256; ++it) {
            const int idx = it * 256 + tid;
            const int l = idx >> 2, q = idx & 3;
            const size_t row = (size_t)(b * SEQ + l0 + l);
            const float4 dv = *(const float4*)&delta[row * D_INNER + d0 + q * 4];
            const float4 xv = *(const float4*)&xrp  [row * D_INNER + d0 + q * 4];
            float2* o = &sDX[l * 16 + q * 4];
            o[0] = make_float2(dv.x, xv.x);
            o[1] = make_float2(dv.y, xv.y);
            o[2] = make_float2(dv.z, xv.z);
            o[3] = make_float2(dv.w, xv.w);
        }
        #pragma unroll
        for (int it = 0; it < CHUNK * 8 / 256; ++it) {
            const int idx = it * 256 + tid;
            const int l = idx >> 3, q = idx & 7;
            const size_t row = (size_t)(b * SEQ + l0 + l);
            const float4 v = *(const float4*)&dbc[row * 64 + 32 + q * 4];
            float* base = (float*)&sBC[l * 16];
            if (q < 4) {
                const int c = q * 4;
                base[2*(c+0)] = v.x; base[2*(c+1)] = v.y; base[2*(c+2)] = v.z; base[2*(c+3)] = v.w;
            } else {
                const int c = (q - 4) * 4;
                base[2*(c+0)+1] = v.x; base[2*(c+1)+1] = v.y; base[2*(c+2)+1] = v.z; base[2*(c+3)+1] = v.w;
            }
        }
        __syncthreads();

        #pragma unroll 4
        for (int l = 0; l < CHUNK; ++l) {
            const float2 dx = sDX[l * 16 + dl];
            const float2 bc = sBC[l * 16 + n];
            const float e = __expf(dx.x * An);
            h = fmaf(e, h, dx.x * dx.y * bc.x);
            const float p = rowsum16(h * bc.y);
            if (n == 0) sY[l * 16 + dl] = fmaf(Dd, dx.y, p);
        }
        __syncthreads();

        #pragma unroll
        for (int it = 0; it < CHUNK * 4 / 256; ++it) {
            const int idx = it * 256 + tid;
            const int l = idx >> 2, q = idx & 3;
            const size_t row = (size_t)(b * SEQ + l0 + l);
            const float4 g4 = *(const float4*)&xz[row * 2 * D_INNER + D_INNER + d0 + q * 4];
            const float4 yv = *(const float4*)&sY[l * 16 + q * 4];
            ushort4 o;
            o.x = f2bf(yv.x * g4.x); o.y = f2bf(yv.y * g4.y);
            o.z = f2bf(yv.z * g4.z); o.w = f2bf(yv.w * g4.w);
            *(ushort4*)&y[row * D_INNER + d0 + q * 4] = o;
        }
    }
}

// d1[b,j] = relu(h[b,last,:] @ w1[j,:] + b1[j])
__global__ __launch_bounds__(256) void dec1_kernel(
    const float* __restrict__ h, const float* __restrict__ w1,
    const float* __restrict__ b1, float* __restrict__ d1)
{
    __shared__ __align__(16) float hr[D_MODEL];
    const int b = blockIdx.x, j = threadIdx.x;
    const float* row = h + ((size_t)(b * SEQ + SEQ - 1)) * D_MODEL;
    hr[j] = row[j];
    hr[j + 256] = row[j + 256];
    __syncthreads();
    float acc = b1[j];
    const float* wr = w1 + (size_t)j * D_MODEL;
    for (int k = 0; k < D_MODEL; k += 4) {
        const float4 wv = *(const float4*)&wr[k];
        const float4 hv = *(const float4*)&hr[k];
        acc = fmaf(wv.x, hv.x, acc); acc = fmaf(wv.y, hv.y, acc);
        acc = fmaf(wv.z, hv.z, acc); acc = fmaf(wv.w, hv.w, acc);
    }
    d1[b * 256 + j] = fmaxf(acc, 0.f);
}

__global__ void dec2_kernel(const float* __restrict__ d1, const float* __restrict__ w2,
                            const float* __restrict__ b2, float* __restrict__ out)
{
    const int b = blockIdx.x, t = threadIdx.x;
    float acc = 0.f;
    for (int k = t; k < 256; k += 64) acc = fmaf(d1[b * 256 + k], w2[k], acc);
    #pragma unroll
    for (int off = 32; off > 0; off >>= 1) acc += __shfl_down(acc, off, 64);
    if (t == 0) out[b] = acc + b2[0];
}

extern "C" void kernel_launch(void* const* d_in, const int* in_sizes, int n_in,
                              void* d_out, int out_size, void* d_ws, size_t ws_size,
                              hipStream_t stream)
{
    const float* x      = (const float*)d_in[0];
    const float* enc_w  = (const float*)d_in[1];
    const float* enc_b  = (const float*)d_in[2];
    const float* in_w   = (const float*)d_in[3];
    const float* conv_w = (const float*)d_in[4];
    const float* conv_b = (const float*)d_in[5];
    const float* xp_w   = (const float*)d_in[6];
    const float* dtp_w  = (const float*)d_in[7];
    const float* dtp_b  = (const float*)d_in[8];
    const float* A_log  = (const float*)d_in[9];
    const float* Dp     = (const float*)d_in[10];
    const float* out_w  = (const float*)d_in[11];
    const float* norm_w = (const float*)d_in[12];
    const float* dec_w1 = (const float*)d_in[13];
    const float* dec_b1 = (const float*)d_in[14];
    const float* dec_w2 = (const float*)d_in[15];
    const float* dec_b2 = (const float*)d_in[16];
    float* out = (float*)d_out;

    // workspace layout
    float* ws    = (float*)d_ws;
    float* h     = ws;                                   // NTOK*512
    float* xz    = h     + (size_t)NTOK * D_MODEL;       // NTOK*2048
    float* xr    = xz    + (size_t)NTOK * 2 * D_INNER;   // NTOK*1024
    float* delta = xr    + (size_t)NTOK * D_INNER;       // NTOK*1024
    float* dbc   = delta + (size_t)NTOK * D_INNER;       // NTOK*64
    float* d1    = dbc   + (size_t)NTOK * 64;            // 2048
    unsigned short* xn_bf  = (unsigned short*)(d1 + 2048);               // NTOK*512
    unsigned short* y_bf   = xn_bf  + (size_t)NTOK * D_MODEL;            // NTOK*1024
    unsigned short* inw_bf = y_bf   + (size_t)NTOK * D_INNER;            // 4*2048*512
    unsigned short* outw_bf= inw_bf + (size_t)N_LAYERS * 2 * D_INNER * D_MODEL;  // 4*512*1024

    const int n_inw  = N_LAYERS * 2 * D_INNER * D_MODEL;   // 4194304
    const int n_outw = N_LAYERS * D_MODEL * D_INNER;       // 2097152
    cast_bf16_kernel<<<(n_inw / 4 + 255) / 256, 256, 0, stream>>>(in_w,  inw_bf,  n_inw);
    cast_bf16_kernel<<<(n_outw / 4 + 255) / 256, 256, 0, stream>>>(out_w, outw_bf, n_outw);

    // encoder: h = x @ enc_w.T + enc_b   (fp32, K=32)
    gemm_bt64<<<dim3(D_MODEL / 64, NTOK / 64), 256, 0, stream>>>(
        x, IN_DIM, enc_w, enc_b, nullptr, h, D_MODEL, IN_DIM, 0, D_MODEL);

    for (int i = 0; i < N_LAYERS; ++i) {
        rmsnorm_kernel<<<NTOK, 256, 0, stream>>>(h, norm_w + (size_t)i * D_MODEL, xn_bf);

        // xz = xn @ in_proj_w[i].T   (4096 x 2048, K=512)  [bf16 MFMA]
        gemm_mfma<128, 128><<<dim3(2 * D_INNER / 128, NTOK / 128), 256, 0, stream>>>(
            xn_bf, D_MODEL, inw_bf + (size_t)i * 2 * D_INNER * D_MODEL,
            nullptr, xz, 2 * D_INNER, D_MODEL);

        // xr = silu(causal_dwconv(xz[:, :D_INNER]) + cb); xz z-half -> silu in place
        conv_silu_kernel<<<NTOK * 2 * D_INNER / 256, 256, 0, stream>>>(
            xz, conv_w + (size_t)i * D_INNER * D_CONV, conv_b + (size_t)i * D_INNER, xr);

        // dbc = xr @ x_proj_w[i].T   (4096 x 64, K=1024)  [fp32]
        gemm_bt64<<<dim3(1, NTOK / 64), 256, 0, stream>>>(
            xr, D_INNER, xp_w + (size_t)i * 64 * D_INNER,
            nullptr, nullptr, dbc, 64, D_INNER, 0, 64);

        // delta = softplus(dbc[:, :32] @ dt_proj_w[i].T + dt_proj_b[i])  [fp32, K=32]
        gemm_bt64<<<dim3(D_INNER / 64, NTOK / 64), 256, 0, stream>>>(
            dbc, 64, dtp_w + (size_t)i * D_INNER * DT_RANK,
            dtp_b + (size_t)i * D_INNER, nullptr, delta, D_INNER, DT_RANK, 1, D_INNER);

        // selective scan + D skip + gate; y -> bf16
        scan_kernel<<<dim3(D_INNER / 16, BATCH), 256, 0, stream>>>(
            delta, xr, dbc, xz,
            A_log + (size_t)i * D_INNER * D_STATE, Dp + (size_t)i * D_INNER, y_bf);

        // h = h + y @ out_proj_w[i].T   (4096 x 512, K=1024)  [bf16 MFMA]
        gemm_mfma<128, 64><<<dim3(D_MODEL / 64, NTOK / 128), 256, 0, stream>>>(
            y_bf, D_INNER, outw_bf + (size_t)i * D_MODEL * D_INNER,
            h, h, D_MODEL, D_INNER);
    }

    dec1_kernel<<<BATCH, 256, 0, stream>>>(h, dec_w1, dec_b1, d1);
    dec2_kernel<<<BATCH, 64, 0, stream>>>(d1, dec_w2, dec_b2, out);
}

// Round 6
// 1030.659 us; speedup vs baseline: 2.5347x; 1.0434x over previous
//
#include <hip/hip_runtime.h>
#include <math.h>

#define BATCH   8
#define SEQ     512
#define IN_DIM  32
#define D_MODEL 512
#define N_LAYERS 4
#define D_INNER 1024
#define D_STATE 16
#define D_CONV  4
#define DT_RANK 32
#define NTOK    (BATCH * SEQ)   // 4096
#define CHUNK   128             // scan L-chunk staged in LDS

typedef __attribute__((ext_vector_type(8))) short short8_t;
typedef __attribute__((ext_vector_type(4))) float floatx4;

__device__ __forceinline__ float sigmoidf_(float x) { return 1.f / (1.f + __expf(-x)); }

// fp32 -> bf16 round-to-nearest-even (finite inputs)
__device__ __forceinline__ unsigned short f2bf(float f) {
    unsigned int u = __float_as_uint(f);
    return (unsigned short)((u + 0x7fffu + ((u >> 16) & 1u)) >> 16);
}

// sum x across each 16-lane row group via DPP (VALU pipe, no LDS traffic)
__device__ __forceinline__ float rowsum16(float x) {
    int t;
    t = __builtin_amdgcn_update_dpp(0, __float_as_int(x), 0xB1, 0xF, 0xF, true);  // quad_perm [1,0,3,2]
    x += __int_as_float(t);
    t = __builtin_amdgcn_update_dpp(0, __float_as_int(x), 0x4E, 0xF, 0xF, true);  // quad_perm [2,3,0,1]
    x += __int_as_float(t);
    t = __builtin_amdgcn_update_dpp(0, __float_as_int(x), 0x124, 0xF, 0xF, true); // row_ror:4
    x += __int_as_float(t);
    t = __builtin_amdgcn_update_dpp(0, __float_as_int(x), 0x128, 0xF, 0xF, true); // row_ror:8
    x += __int_as_float(t);
    return x;
}

// elementwise fp32 -> bf16 cast; n % 4 == 0
__global__ __launch_bounds__(256) void cast_bf16_kernel(
    const float* __restrict__ in, unsigned short* __restrict__ out, int n)
{
    const int i = (blockIdx.x * 256 + threadIdx.x) * 4;
    if (i >= n) return;
    const float4 v = *(const float4*)&in[i];
    ushort4 o;
    o.x = f2bf(v.x); o.y = f2bf(v.y); o.z = f2bf(v.z); o.w = f2bf(v.w);
    *(ushort4*)&out[i] = o;
}

// ---------------- bf16 MFMA GEMM ----------------
// C[m,n] = act( dot(A[m,0:K], W[n,0:K]) + bias[n] ) + R[m,n]; A,W bf16, C/R fp32.
// Optional Cbf mirror (bf16 copy of C). act: 0=none, 1=softplus.
// Block tile BM x BN, 4 waves in 2x2, BK=32. LDS rows padded to 40 bf16 -> 2-way conflicts only (free).
template<int BM, int BN>
__global__ __launch_bounds__(256) void gemm_mfma(
    const unsigned short* __restrict__ A, int lda,
    const unsigned short* __restrict__ W, int ldw,
    const float* __restrict__ bias,
    const float* __restrict__ R,
    float* __restrict__ C, int ldc,
    unsigned short* __restrict__ Cbf,
    int K, int act)
{
    constexpr int MT = BM / 32;
    constexpr int NT = BN / 32;
    constexpr int LDSP = 40;
    __shared__ __align__(16) unsigned short sA[BM * LDSP];
    __shared__ __align__(16) unsigned short sB[BN * LDSP];

    const int tid  = threadIdx.x;
    const int lane = tid & 63;
    const int wave = tid >> 6;
    const int wm0  = (wave >> 1) * (BM / 2);
    const int wn0  = (wave & 1) * (BN / 2);
    const int lrow = lane & 15;
    const int lko  = (lane >> 4) * 8;
    const int m0 = blockIdx.y * BM;
    const int n0 = blockIdx.x * BN;

    floatx4 acc[MT][NT];
    #pragma unroll
    for (int mt = 0; mt < MT; ++mt)
        #pragma unroll
        for (int nt = 0; nt < NT; ++nt)
            acc[mt][nt] = (floatx4){0.f, 0.f, 0.f, 0.f};

    for (int k0 = 0; k0 < K; k0 += 32) {
        #pragma unroll
        for (int it = 0; it < BM * 4 / 256; ++it) {
            const int idx = it * 256 + tid;
            const int r = idx >> 2, c = (idx & 3) * 8;
            *(short8_t*)&sA[r * LDSP + c] = *(const short8_t*)&A[(size_t)(m0 + r) * lda + k0 + c];
        }
        #pragma unroll
        for (int it = 0; it < BN * 4 / 256; ++it) {
            const int idx = it * 256 + tid;
            const int r = idx >> 2, c = (idx & 3) * 8;
            *(short8_t*)&sB[r * LDSP + c] = *(const short8_t*)&W[(size_t)(n0 + r) * ldw + k0 + c];
        }
        __syncthreads();
        short8_t af[MT], bfr[NT];
        #pragma unroll
        for (int mt = 0; mt < MT; ++mt)
            af[mt] = *(const short8_t*)&sA[(wm0 + mt * 16 + lrow) * LDSP + lko];
        #pragma unroll
        for (int nt = 0; nt < NT; ++nt)
            bfr[nt] = *(const short8_t*)&sB[(wn0 + nt * 16 + lrow) * LDSP + lko];
        #pragma unroll
        for (int mt = 0; mt < MT; ++mt)
            #pragma unroll
            for (int nt = 0; nt < NT; ++nt)
                acc[mt][nt] = __builtin_amdgcn_mfma_f32_16x16x32_bf16(af[mt], bfr[nt], acc[mt][nt], 0, 0, 0);
        __syncthreads();
    }

    #pragma unroll
    for (int mt = 0; mt < MT; ++mt) {
        const int mbase = m0 + wm0 + mt * 16 + (lane >> 4) * 4;
        #pragma unroll
        for (int nt = 0; nt < NT; ++nt) {
            const int n = n0 + wn0 + nt * 16 + (lane & 15);
            #pragma unroll
            for (int r = 0; r < 4; ++r) {
                float v = acc[mt][nt][r];
                if (bias) v += bias[n];
                if (act == 1) v = (v > 20.f) ? v : log1pf(__expf(v));   // softplus
                if (R) v += R[(size_t)(mbase + r) * ldc + n];
                C[(size_t)(mbase + r) * ldc + n] = v;
                if (Cbf) Cbf[(size_t)(mbase + r) * ldc + n] = f2bf(v);
            }
        }
    }
}

// ---------------- fp32 vector GEMM (encoder only) ----------------
__global__ __launch_bounds__(256) void gemm_bt64(
    const float* __restrict__ A, int lda,
    const float* __restrict__ W,
    const float* __restrict__ bias,
    const float* __restrict__ R,
    float* __restrict__ C,
    int N, int K, int act, int ldc)
{
    __shared__ __align__(16) float As[16][64];
    __shared__ __align__(16) float Ws[16][64];
    const int tid = threadIdx.x;
    const int tx = tid & 15, ty = tid >> 4;
    const int m0 = blockIdx.y * 64, n0 = blockIdx.x * 64;
    const int lm = tid >> 2;
    const int lk = (tid & 3) * 4;

    float acc[4][4] = {};
    for (int k0 = 0; k0 < K; k0 += 16) {
        float4 av = *(const float4*)&A[(size_t)(m0 + lm) * lda + k0 + lk];
        float4 wv = *(const float4*)&W[(size_t)(n0 + lm) * K   + k0 + lk];
        As[lk + 0][lm] = av.x; As[lk + 1][lm] = av.y; As[lk + 2][lm] = av.z; As[lk + 3][lm] = av.w;
        Ws[lk + 0][lm] = wv.x; Ws[lk + 1][lm] = wv.y; Ws[lk + 2][lm] = wv.z; Ws[lk + 3][lm] = wv.w;
        __syncthreads();
        #pragma unroll
        for (int k = 0; k < 16; ++k) {
            float4 a4 = *(const float4*)&As[k][ty * 4];
            float4 b4 = *(const float4*)&Ws[k][tx * 4];
            float a[4] = {a4.x, a4.y, a4.z, a4.w};
            float b[4] = {b4.x, b4.y, b4.z, b4.w};
            #pragma unroll
            for (int i = 0; i < 4; ++i)
                #pragma unroll
                for (int j = 0; j < 4; ++j)
                    acc[i][j] = fmaf(a[i], b[j], acc[i][j]);
        }
        __syncthreads();
    }
    #pragma unroll
    for (int i = 0; i < 4; ++i) {
        const int m = m0 + ty * 4 + i;
        #pragma unroll
        for (int j = 0; j < 4; ++j) {
            const int n = n0 + tx * 4 + j;
            float v = acc[i][j];
            if (bias) v += bias[n];
            if (act == 1) v = (v > 20.f) ? v : log1pf(__expf(v));
            if (R) v += R[(size_t)m * ldc + n];
            C[(size_t)m * ldc + n] = v;
        }
    }
}

// xn_bf[tok,:] = bf16( h[tok,:] * rsqrt(mean(h^2)+1e-5) * w )
__global__ __launch_bounds__(256) void rmsnorm_kernel(
    const float* __restrict__ h, const float* __restrict__ w, unsigned short* __restrict__ xn)
{
    const int tok = blockIdx.x, tid = threadIdx.x;
    const float* row = h + (size_t)tok * D_MODEL;
    float v0 = row[tid], v1 = row[tid + 256];
    float s = v0 * v0 + v1 * v1;
    #pragma unroll
    for (int off = 32; off > 0; off >>= 1) s += __shfl_down(s, off, 64);
    __shared__ float ss[4];
    if ((tid & 63) == 0) ss[tid >> 6] = s;
    __syncthreads();
    const float total = ss[0] + ss[1] + ss[2] + ss[3];
    const float scale = rsqrtf(total * (1.f / (float)D_MODEL) + 1e-5f);
    unsigned short* orow = xn + (size_t)tok * D_MODEL;
    orow[tid]       = f2bf(v0 * scale * w[tid]);
    orow[tid + 256] = f2bf(v1 * scale * w[tid + 256]);
}

// c < D_INNER:  xr[tok,c] = silu(causal_dwconv(xz[:, c]) + cb[c])  (+ bf16 mirror)
// c >= D_INNER: xz[tok,c] = silu(xz[tok,c])   (gate precompute, in-place on z-half)
__global__ __launch_bounds__(256) void conv_silu_kernel(
    float* __restrict__ xz, const float* __restrict__ cw,
    const float* __restrict__ cb, float* __restrict__ xr,
    unsigned short* __restrict__ xr_bf)
{
    const int idx = blockIdx.x * 256 + threadIdx.x;   // over NTOK*2*D_INNER
    const int c   = idx & (2 * D_INNER - 1);
    const int tok = idx >> 11;
    if (c < D_INNER) {
        const int l = tok & (SEQ - 1);
        float acc = cb[c];
        #pragma unroll
        for (int k = 0; k < D_CONV; ++k) {
            const int t = l - (D_CONV - 1) + k;
            if (t >= 0)
                acc = fmaf(xz[(size_t)(tok + t - l) * (2 * D_INNER) + c], cw[c * D_CONV + k], acc);
        }
        const float v = acc * sigmoidf_(acc);
        xr[(size_t)tok * D_INNER + c] = v;
        xr_bf[(size_t)tok * D_INNER + c] = f2bf(v);
    } else {
        const float v = xz[idx];
        xz[idx] = v * sigmoidf_(v);
    }
}

// selective scan, LDS-chunked (see R3/R4). Output y bf16 (feeds MFMA out_proj).
__global__ __launch_bounds__(256) void scan_kernel(
    const float* __restrict__ delta, const float* __restrict__ xrp,
    const float* __restrict__ dbc,   const float* __restrict__ xz,
    const float* __restrict__ A_log, const float* __restrict__ Dp,
    unsigned short* __restrict__ y)
{
    __shared__ __align__(16) float2 sDX[CHUNK * 16];
    __shared__ __align__(16) float2 sBC[CHUNK * 16];
    __shared__ __align__(16) float  sY [CHUNK * 16];
    const int b   = blockIdx.y;
    const int tid = threadIdx.x;
    const int n   = tid & 15;
    const int dl  = tid >> 4;
    const int d0  = blockIdx.x * 16;
    const int d   = d0 + dl;

    const float An = -__expf(A_log[(size_t)d * D_STATE + n]);
    const float Dd = Dp[d];

    float h = 0.f;
    for (int l0 = 0; l0 < SEQ; l0 += CHUNK) {
        #pragma unroll
        for (int it = 0; it < CHUNK * 4 / 256; ++it) {
            const int idx = it * 256 + tid;
            const int l = idx >> 2, q = idx & 3;
            const size_t row = (size_t)(b * SEQ + l0 + l);
            const float4 dv = *(const float4*)&delta[row * D_INNER + d0 + q * 4];
            const float4 xv = *(const float4*)&xrp  [row * D_INNER + d0 + q * 4];
            float2* o = &sDX[l * 16 + q * 4];
            o[0] = make_float2(dv.x, xv.x);
            o[1] = make_float2(dv.y, xv.y);
            o[2] = make_float2(dv.z, xv.z);
            o[3] = make_float2(dv.w, xv.w);
        }
        #pragma unroll
        for (int it = 0; it < CHUNK * 8 / 256; ++it) {
            const int idx = it * 256 + tid;
            const int l = idx >> 3, q = idx & 7;
            const size_t row = (size_t)(b * SEQ + l0 + l);
            const float4 v = *(const float4*)&dbc[row * 64 + 32 + q * 4];
            float* base = (float*)&sBC[l * 16];
            if (q < 4) {
                const int c = q * 4;
                base[2*(c+0)] = v.x; base[2*(c+1)] = v.y; base[2*(c+2)] = v.z; base[2*(c+3)] = v.w;
            } else {
                const int c = (q - 4) * 4;
                base[2*(c+0)+1] = v.x; base[2*(c+1)+1] = v.y; base[2*(c+2)+1] = v.z; base[2*(c+3)+1] = v.w;
            }
        }
        __syncthreads();

        #pragma unroll 4
        for (int l = 0; l < CHUNK; ++l) {
            const float2 dx = sDX[l * 16 + dl];
            const float2 bc = sBC[l * 16 + n];
            const float e = __expf(dx.x * An);
            h = fmaf(e, h, dx.x * dx.y * bc.x);
            const float p = rowsum16(h * bc.y);
            if (n == 0) sY[l * 16 + dl] = fmaf(Dd, dx.y, p);
        }
        __syncthreads();

        #pragma unroll
        for (int it = 0; it < CHUNK * 4 / 256; ++it) {
            const int idx = it * 256 + tid;
            const int l = idx >> 2, q = idx & 3;
            const size_t row = (size_t)(b * SEQ + l0 + l);
            const float4 g4 = *(const float4*)&xz[row * 2 * D_INNER + D_INNER + d0 + q * 4];
            const float4 yv = *(const float4*)&sY[l * 16 + q * 4];
            ushort4 o;
            o.x = f2bf(yv.x * g4.x); o.y = f2bf(yv.y * g4.y);
            o.z = f2bf(yv.z * g4.z); o.w = f2bf(yv.w * g4.w);
            *(ushort4*)&y[row * D_INNER + d0 + q * 4] = o;
        }
    }
}

// d1[b,j] = relu(h[b,last,:] @ w1[j,:] + b1[j])
__global__ __launch_bounds__(256) void dec1_kernel(
    const float* __restrict__ h, const float* __restrict__ w1,
    const float* __restrict__ b1, float* __restrict__ d1)
{
    __shared__ __align__(16) float hr[D_MODEL];
    const int b = blockIdx.x, j = threadIdx.x;
    const float* row = h + ((size_t)(b * SEQ + SEQ - 1)) * D_MODEL;
    hr[j] = row[j];
    hr[j + 256] = row[j + 256];
    __syncthreads();
    float acc = b1[j];
    const float* wr = w1 + (size_t)j * D_MODEL;
    for (int k = 0; k < D_MODEL; k += 4) {
        const float4 wv = *(const float4*)&wr[k];
        const float4 hv = *(const float4*)&hr[k];
        acc = fmaf(wv.x, hv.x, acc); acc = fmaf(wv.y, hv.y, acc);
        acc = fmaf(wv.z, hv.z, acc); acc = fmaf(wv.w, hv.w, acc);
    }
    d1[b * 256 + j] = fmaxf(acc, 0.f);
}

__global__ void dec2_kernel(const float* __restrict__ d1, const float* __restrict__ w2,
                            const float* __restrict__ b2, float* __restrict__ out)
{
    const int b = blockIdx.x, t = threadIdx.x;
    float acc = 0.f;
    for (int k = t; k < 256; k += 64) acc = fmaf(d1[b * 256 + k], w2[k], acc);
    #pragma unroll
    for (int off = 32; off > 0; off >>= 1) acc += __shfl_down(acc, off, 64);
    if (t == 0) out[b] = acc + b2[0];
}

extern "C" void kernel_launch(void* const* d_in, const int* in_sizes, int n_in,
                              void* d_out, int out_size, void* d_ws, size_t ws_size,
                              hipStream_t stream)
{
    const float* x      = (const float*)d_in[0];
    const float* enc_w  = (const float*)d_in[1];
    const float* enc_b  = (const float*)d_in[2];
    const float* in_w   = (const float*)d_in[3];
    const float* conv_w = (const float*)d_in[4];
    const float* conv_b = (const float*)d_in[5];
    const float* xp_w   = (const float*)d_in[6];
    const float* dtp_w  = (const float*)d_in[7];
    const float* dtp_b  = (const float*)d_in[8];
    const float* A_log  = (const float*)d_in[9];
    const float* Dp     = (const float*)d_in[10];
    const float* out_w  = (const float*)d_in[11];
    const float* norm_w = (const float*)d_in[12];
    const float* dec_w1 = (const float*)d_in[13];
    const float* dec_b1 = (const float*)d_in[14];
    const float* dec_w2 = (const float*)d_in[15];
    const float* dec_b2 = (const float*)d_in[16];
    float* out = (float*)d_out;

    // workspace layout
    float* ws    = (float*)d_ws;
    float* h     = ws;                                   // NTOK*512
    float* xz    = h     + (size_t)NTOK * D_MODEL;       // NTOK*2048
    float* xr    = xz    + (size_t)NTOK * 2 * D_INNER;   // NTOK*1024
    float* delta = xr    + (size_t)NTOK * D_INNER;       // NTOK*1024
    float* dbc   = delta + (size_t)NTOK * D_INNER;       // NTOK*64
    float* d1    = dbc   + (size_t)NTOK * 64;            // 2048
    unsigned short* xn_bf   = (unsigned short*)(d1 + 2048);                          // NTOK*512
    unsigned short* y_bf    = xn_bf   + (size_t)NTOK * D_MODEL;                      // NTOK*1024
    unsigned short* xr_bf   = y_bf    + (size_t)NTOK * D_INNER;                      // NTOK*1024
    unsigned short* dbc_bf  = xr_bf   + (size_t)NTOK * D_INNER;                      // NTOK*64
    unsigned short* inw_bf  = dbc_bf  + (size_t)NTOK * 64;                           // 4*2048*512
    unsigned short* outw_bf = inw_bf  + (size_t)N_LAYERS * 2 * D_INNER * D_MODEL;    // 4*512*1024
    unsigned short* xpw_bf  = outw_bf + (size_t)N_LAYERS * D_MODEL * D_INNER;        // 4*64*1024
    unsigned short* dtpw_bf = xpw_bf  + (size_t)N_LAYERS * 64 * D_INNER;             // 4*1024*32

    const int n_inw  = N_LAYERS * 2 * D_INNER * D_MODEL;   // 4194304
    const int n_outw = N_LAYERS * D_MODEL * D_INNER;       // 2097152
    const int n_xpw  = N_LAYERS * 64 * D_INNER;            // 262144
    const int n_dtpw = N_LAYERS * D_INNER * DT_RANK;       // 131072
    cast_bf16_kernel<<<(n_inw  / 4 + 255) / 256, 256, 0, stream>>>(in_w,  inw_bf,  n_inw);
    cast_bf16_kernel<<<(n_outw / 4 + 255) / 256, 256, 0, stream>>>(out_w, outw_bf, n_outw);
    cast_bf16_kernel<<<(n_xpw  / 4 + 255) / 256, 256, 0, stream>>>(xp_w,  xpw_bf,  n_xpw);
    cast_bf16_kernel<<<(n_dtpw / 4 + 255) / 256, 256, 0, stream>>>(dtp_w, dtpw_bf, n_dtpw);

    // encoder: h = x @ enc_w.T + enc_b   (fp32, K=32)
    gemm_bt64<<<dim3(D_MODEL / 64, NTOK / 64), 256, 0, stream>>>(
        x, IN_DIM, enc_w, enc_b, nullptr, h, D_MODEL, IN_DIM, 0, D_MODEL);

    for (int i = 0; i < N_LAYERS; ++i) {
        rmsnorm_kernel<<<NTOK, 256, 0, stream>>>(h, norm_w + (size_t)i * D_MODEL, xn_bf);

        // xz = xn @ in_proj_w[i].T   (4096 x 2048, K=512)  [bf16 MFMA]
        gemm_mfma<128, 128><<<dim3(2 * D_INNER / 128, NTOK / 128), 256, 0, stream>>>(
            xn_bf, D_MODEL, inw_bf + (size_t)i * 2 * D_INNER * D_MODEL, D_MODEL,
            nullptr, nullptr, xz, 2 * D_INNER, nullptr, D_MODEL, 0);

        // xr = silu(causal_dwconv(xz[:, :D_INNER]) + cb) (+bf16 mirror); z-half silu in place
        conv_silu_kernel<<<NTOK * 2 * D_INNER / 256, 256, 0, stream>>>(
            xz, conv_w + (size_t)i * D_INNER * D_CONV, conv_b + (size_t)i * D_INNER, xr, xr_bf);

        // dbc = xr @ x_proj_w[i].T   (4096 x 64, K=1024)  [bf16 MFMA, fp32 + bf16 out]
        gemm_mfma<64, 64><<<dim3(1, NTOK / 64), 256, 0, stream>>>(
            xr_bf, D_INNER, xpw_bf + (size_t)i * 64 * D_INNER, D_INNER,
            nullptr, nullptr, dbc, 64, dbc_bf, D_INNER, 0);

        // delta = softplus(dbc[:, :32] @ dt_proj_w[i].T + dt_proj_b[i])  [bf16 MFMA, K=32]
        gemm_mfma<128, 128><<<dim3(D_INNER / 128, NTOK / 128), 256, 0, stream>>>(
            dbc_bf, 64, dtpw_bf + (size_t)i * D_INNER * DT_RANK, DT_RANK,
            dtp_b + (size_t)i * D_INNER, nullptr, delta, D_INNER, nullptr, DT_RANK, 1);

        // selective scan + D skip + gate; y -> bf16
        scan_kernel<<<dim3(D_INNER / 16, BATCH), 256, 0, stream>>>(
            delta, xr, dbc, xz,
            A_log + (size_t)i * D_INNER * D_STATE, Dp + (size_t)i * D_INNER, y_bf);

        // h = h + y @ out_proj_w[i].T   (4096 x 512, K=1024)  [bf16 MFMA]
        gemm_mfma<128, 64><<<dim3(D_MODEL / 64, NTOK / 128), 256, 0, stream>>>(
            y_bf, D_INNER, outw_bf + (size_t)i * D_MODEL * D_INNER, D_INNER,
            nullptr, h, h, D_MODEL, nullptr, D_INNER, 0);
    }

    dec1_kernel<<<BATCH, 256, 0, stream>>>(h, dec_w1, dec_b1, d1);
    dec2_kernel<<<BATCH, 64, 0, stream>>>(d1, dec_w2, dec_b2, out);
}